// Round 3
// baseline (175.338 us; speedup 1.0000x reference)
//
#include <hip/hip_runtime.h>
#include <hip/hip_bf16.h>
#include <stdint.h>

// Shape fixed by reference: B=2, S=1024 -> M=2048; N=4096; K=4096
#define M_DIM 2048
#define N_DIM 4096
#define K_DIM 4096

#define BM 128
#define BN 256
#define BK 128            // int8 elements per K-tile = 128 B per row

#define NSLOT 3           // ring depth -> 2-deep prefetch -> counted vmcnt(6)
#define ASLOT (BM * BK)   // 16 KiB per A slot
#define BSLOT (BN * BK)   // 32 KiB per B slot

#define NT (K_DIM / BK)   // 32 K-tiles

typedef __attribute__((ext_vector_type(4))) int   int4v;
typedef __attribute__((ext_vector_type(4))) float f32x4;

__device__ __forceinline__ void load_lds16(const void* g, void* l) {
    __builtin_amdgcn_global_load_lds(
        (const __attribute__((address_space(1))) void*)g,
        (__attribute__((address_space(3))) void*)l,
        16, 0, 0);
}

// ---------- x: fp32 [M,K] -> int8 per-row dynamic quant; sx[row] = rowmax/127 ----------
__global__ __launch_bounds__(256) void quant_x(const float* __restrict__ x,
                                               int8_t* __restrict__ Aq,
                                               float* __restrict__ sx) {
    const int row = blockIdx.x;
    const int tid = threadIdx.x;
    const float4* xr = (const float4*)(x + (size_t)row * K_DIM);

    float4 v[4];
    float mx = 0.f;
#pragma unroll
    for (int p = 0; p < 4; p++) {
        v[p] = xr[p * 256 + tid];
        mx = fmaxf(mx, fmaxf(fmaxf(fabsf(v[p].x), fabsf(v[p].y)),
                             fmaxf(fabsf(v[p].z), fabsf(v[p].w))));
    }
#pragma unroll
    for (int off = 32; off >= 1; off >>= 1)
        mx = fmaxf(mx, __shfl_xor(mx, off, 64));

    __shared__ float wmax[4];
    __shared__ float smax;
    if ((tid & 63) == 0) wmax[tid >> 6] = mx;
    __syncthreads();
    if (tid == 0) {
        float m = fmaxf(fmaxf(wmax[0], wmax[1]), fmaxf(wmax[2], wmax[3]));
        m = fmaxf(m, 1e-20f);
        smax = m;
        sx[row] = m * (1.0f / 127.0f);
    }
    __syncthreads();
    const float inv = 127.0f / smax;

    int* out = (int*)Aq + (size_t)row * (K_DIM / 4);
#pragma unroll
    for (int p = 0; p < 4; p++) {
        int q0 = (int)__builtin_rintf(v[p].x * inv);
        int q1 = (int)__builtin_rintf(v[p].y * inv);
        int q2 = (int)__builtin_rintf(v[p].z * inv);
        int q3 = (int)__builtin_rintf(v[p].w * inv);
        q0 = max(-127, min(127, q0)); q1 = max(-127, min(127, q1));
        q2 = max(-127, min(127, q2)); q3 = max(-127, min(127, q3));
        out[p * 256 + tid] = (q0 & 255) | ((q1 & 255) << 8) |
                             ((q2 & 255) << 16) | ((q3 & 255) << 24);
    }
}

// ---------- w: int32 [N,K] (values in [-128,127]) -> int8, exact narrowing ----------
__global__ __launch_bounds__(256) void cvt_w8(const int* __restrict__ w,
                                              int8_t* __restrict__ Bq) {
    size_t i = ((size_t)blockIdx.x * 256 + threadIdx.x) * 16;
    int4 a0 = *(const int4*)(w + i);
    int4 a1 = *(const int4*)(w + i + 4);
    int4 a2 = *(const int4*)(w + i + 8);
    int4 a3 = *(const int4*)(w + i + 12);
    uint4 t;
    t.x = (a0.x & 255) | ((a0.y & 255) << 8) | ((a0.z & 255) << 16) | ((a0.w & 255) << 24);
    t.y = (a1.x & 255) | ((a1.y & 255) << 8) | ((a1.z & 255) << 16) | ((a1.w & 255) << 24);
    t.z = (a2.x & 255) | ((a2.y & 255) << 8) | ((a2.z & 255) << 16) | ((a2.w & 255) << 24);
    t.w = (a3.x & 255) | ((a3.y & 255) << 8) | ((a3.z & 255) << 16) | ((a3.w & 255) << 24);
    *(uint4*)(Bq + i) = t;
}

// ---------- GEMM: C = Aq[M,K] x Bq[N,K]^T (i8 MFMA, i32 acc), epilogue dequant ----------
// r7 == r6 (infra flake retry): counted-vmcnt ring pipeline (T3+T4), 128x256 block,
// 8 waves (2x4) each 64x64. Ring of 3 LDS tile buffers (144 KiB, 1 block/CU),
// prefetch 2 tiles ahead: steady-state wait is s_waitcnt vmcnt(6) (t+1,t+2 loads
// stay in flight across the raw s_barrier) -- never a full drain until the last
// tile. No __syncthreads in the K-loop (would force compiler vmcnt(0) drain).
// Data layout + XOR swizzle identical to the verified r4/r5 kernels: phys colgroup
// p of LDS row r holds global colgroup p ^ (r&7); reads use cp = (h*4+quad) ^
// (l16&7), which cancels exactly (row&7 == l16&7 for all fragment rows). Bank-
// conflict-free (measured 0). setprio(1) wraps each 16-MFMA cluster (T5).
// Slot-reuse safety: barrier(t) is reached by each wave only after its tile-(t-1)
// ds_reads drained (compiler lgkm waits precede the MFMAs that consume them), so
// staging slot (t+2)%3 == (t-1)%3 after barrier(t) is race-free.

__global__ __launch_bounds__(512, 2) void gemm_bt_i8(
    const int8_t* __restrict__ A,      // [M,K] int8
    const int8_t* __restrict__ B,      // [N,K] int8
    const float*  __restrict__ sx,     // [M] row dequant scale
    const float*  __restrict__ scales, // [N]
    const float*  __restrict__ bias,   // [N]
    float* __restrict__ C)             // [M,N]
{
    __shared__ __align__(16) int8_t As[NSLOT * ASLOT];  // 48 KiB
    __shared__ __align__(16) int8_t Bs[NSLOT * BSLOT];  // 96 KiB

    const int tid  = threadIdx.x;

    // T1: XCD-aware swizzle. 256 blocks, 8 XCD chunks of 32 blocks arranged as
    // 8(bm) x 4(bn) tiles per chunk; chunks tile the 16x16 grid as 2x4.
    const int bid   = blockIdx.x;
    const int xcd   = bid & 7;
    const int local = bid >> 3;                       // 0..31
    const int bm    = (xcd >> 2) * 8 + (local >> 2);  // 0..15
    const int bn    = (xcd & 3) * 4 + (local & 3);    // 0..15

    const int lane = tid & 63;
    const int wave = tid >> 6;           // 0..7
    const int wm   = (wave >> 2) * 64;   // 0 or 64      (A rows within 128)
    const int wn   = (wave & 3) * 64;    // 0,64,128,192 (B rows within 256)
    const int l16  = lane & 15;
    const int quad = lane >> 4;
    const int swz  = l16 & 7;

    // Staging: 512 thr x 16 B = 8 KiB per glds instr; A tile = 2 instrs, B = 4.
    // thread t -> segment row = t>>3, phys colgroup = t&7;
    // global colgroup = phys ^ (row&7). LDS byte addr = 16*t within segment.
    const int srow = tid >> 3;           // 0..63
    const int cgp  = tid & 7;
    const int cgl  = cgp ^ (srow & 7);   // (seg*64 + srow)&7 == srow&7 for all seg

    const int8_t* ga = A + (size_t)(bm * BM + srow) * K_DIM + cgl * 16;
    const int8_t* gb = B + (size_t)(bn * BN + srow) * K_DIM + cgl * 16;
    const int la = tid * 16;

#define STAGE(slot, koff) do {                                               \
        load_lds16(ga + (koff),                 As + (slot) * ASLOT + la);   \
        load_lds16(ga + 64 * K_DIM + (koff),    As + (slot) * ASLOT + 8192 + la); \
        load_lds16(gb + (koff),                 Bs + (slot) * BSLOT + la);   \
        load_lds16(gb + 64 * K_DIM + (koff),    Bs + (slot) * BSLOT + 8192 + la); \
        load_lds16(gb + 128 * K_DIM + (koff),   Bs + (slot) * BSLOT + 16384 + la); \
        load_lds16(gb + 192 * K_DIM + (koff),   Bs + (slot) * BSLOT + 24576 + la); \
    } while (0)

    int4v acc[4][4] = {};

#define COMPUTE(slot) do {                                                   \
        const int8_t* Ab = As + (slot) * ASLOT;                              \
        const int8_t* Bb = Bs + (slot) * BSLOT;                              \
        _Pragma("unroll")                                                    \
        for (int h = 0; h < 2; h++) {                                        \
            const int cp = (h * 4 + quad) ^ swz;                             \
            int4v af[4], bfr[4];                                             \
            _Pragma("unroll")                                                \
            for (int i = 0; i < 4; i++)                                      \
                af[i] = *(const int4v*)(Ab + (wm + i * 16 + l16) * BK + cp * 16); \
            _Pragma("unroll")                                                \
            for (int j = 0; j < 4; j++)                                      \
                bfr[j] = *(const int4v*)(Bb + (wn + j * 16 + l16) * BK + cp * 16); \
            __builtin_amdgcn_s_setprio(1);                                   \
            _Pragma("unroll")                                                \
            for (int i = 0; i < 4; i++)                                      \
                _Pragma("unroll")                                            \
                for (int j = 0; j < 4; j++)                                  \
                    acc[i][j] = __builtin_amdgcn_mfma_i32_16x16x64_i8(       \
                        af[i], bfr[j], acc[i][j], 0, 0, 0);                  \
            __builtin_amdgcn_s_setprio(0);                                   \
        }                                                                    \
    } while (0)

    // Prologue: tiles 0 and 1 in flight (12 loads outstanding).
    STAGE(0, 0);
    STAGE(1, BK);

    int s0 = 0, s1 = 1, s2 = 2;   // slots of tiles t, t+1, t+2

    // Main loop: t = 0 .. NT-3. vmcnt(6): own tile-t loads done, tile t+1 (and
    // t+2 after STAGE below) stay in flight. Barrier then makes ALL waves'
    // tile-t loads LDS-visible and frees slot (t+2)%3 for staging.
    for (int t = 0; t < NT - 2; ++t) {
        asm volatile("s_waitcnt vmcnt(6)" ::: "memory");
        __builtin_amdgcn_s_barrier();
        STAGE(s2, (t + 2) * BK);
        COMPUTE(s0);
        const int tmp = s0; s0 = s1; s1 = s2; s2 = tmp;
    }

    // t = NT-2: nothing left to stage; outstanding = tiles NT-2 (6) + NT-1 (6).
    asm volatile("s_waitcnt vmcnt(6)" ::: "memory");
    __builtin_amdgcn_s_barrier();
    COMPUTE(s0);
    { const int tmp = s0; s0 = s1; s1 = s2; s2 = tmp; }

    // t = NT-1: drain the last 6.
    asm volatile("s_waitcnt vmcnt(0)" ::: "memory");
    __builtin_amdgcn_s_barrier();
    COMPUTE(s0);

#undef STAGE
#undef COMPUTE

    // Row dequant scales for this lane's 16 output rows.
    float sxr[16];
#pragma unroll
    for (int i = 0; i < 4; i++)
#pragma unroll
        for (int r = 0; r < 4; r++)
            sxr[i * 4 + r] = sx[bm * BM + wm + i * 16 + quad * 4 + r];

    // Epilogue. C/D layout (shape-determined, verified): col = lane&15, row = quad*4 + reg.
#pragma unroll
    for (int j = 0; j < 4; j++) {
        const int col = bn * BN + wn + j * 16 + l16;
        const float s = scales[col];
        const float b = bias[col];
#pragma unroll
        for (int i = 0; i < 4; i++) {
            const int row0 = bm * BM + wm + i * 16 + quad * 4;
#pragma unroll
            for (int r = 0; r < 4; r++) {
                C[(size_t)(row0 + r) * N_DIM + col] =
                    (float)acc[i][j][r] * (sxr[i * 4 + r] * s) + b;
            }
        }
    }
}

// ---------- launch ----------

extern "C" void kernel_launch(void* const* d_in, const int* in_sizes, int n_in,
                              void* d_out, int out_size, void* d_ws, size_t ws_size,
                              hipStream_t stream) {
    const float* x      = (const float*)d_in[0];   // [2,1024,4096] fp32
    const int*   w      = (const int*)d_in[1];     // [4096,4096] int, values in [-128,127]
    const float* scales = (const float*)d_in[2];   // [4096]
    const float* bias   = (const float*)d_in[3];   // [4096]
    float*       out    = (float*)d_out;           // [2,1024,4096] fp32

    int8_t* Aq = (int8_t*)d_ws;                                        // 8 MiB
    int8_t* Bq = (int8_t*)d_ws + (size_t)M_DIM * K_DIM;                // 16 MiB
    float*  sx = (float*)((int8_t*)d_ws + (size_t)(M_DIM + N_DIM) * K_DIM); // 8 KiB

    quant_x<<<M_DIM, 256, 0, stream>>>(x, Aq, sx);
    cvt_w8<<<(int)((size_t)N_DIM * K_DIM / 16 / 256), 256, 0, stream>>>(w, Bq);

    // 1-D grid of 256 blocks (16 bm x 16 bn), XCD-swizzled inside the kernel.
    gemm_bt_i8<<<256, 512, 0, stream>>>(Aq, Bq, sx, scales, bias, out);
}